// Round 1
// baseline (240.528 us; speedup 1.0000x reference)
//
#include <hip/hip_runtime.h>
#include <hip/hip_bf16.h>

// Problem constants (fixed by setup_inputs)
#define N_NODES   100000
#define MAX_DEG   64
#define NODE_DIM  256
#define NUM_V     8192
#define NSAMP     16
#define GROUP_DIM 4
#define SENTINEL  (N_NODES - 1)

// ---------------- Kernel 1: l = features[ids] @ W + b  ----------------
// C[8192x256] = A[8192x256] @ W[256x256], A rows gathered via ids.
// Tile: BM=64 rows x BN=64 cols per block, BK=16, 256 threads, 4x4 per thread.
#define BM 64
#define BN 64
#define BK 16

__global__ __launch_bounds__(256) void gemm_l_kernel(
    const int* __restrict__ ids,
    const float* __restrict__ features,
    const float* __restrict__ W,
    const float* __restrict__ bias,
    float* __restrict__ l_out) {
  __shared__ float As[BK][BM];   // transposed: As[k][m]
  __shared__ float Ws[BK][BN];
  __shared__ int   nid_s[BM];

  const int tid  = threadIdx.x;
  const int row0 = blockIdx.x * BM;
  const int col0 = blockIdx.y * BN;

  if (tid < BM) nid_s[tid] = ids[row0 + tid];
  __syncthreads();

  const int tx = tid & 15;   // col group 0..15
  const int ty = tid >> 4;   // row group 0..15

  // A-tile load mapping: 4 threads per row, float4 each
  const int am = tid >> 2;          // 0..63 (row within tile)
  const int ak = (tid & 3) * 4;     // 0,4,8,12 (k offset)
  // W-tile load mapping: 16 threads per k-row, float4 each
  const int wk = tid >> 4;          // 0..15
  const int wn = (tid & 15) * 4;    // 0..60

  const size_t a_base = (size_t)nid_s[am] * NODE_DIM + ak;

  float acc[4][4] = {};

  for (int k0 = 0; k0 < NODE_DIM; k0 += BK) {
    const float4 av = *reinterpret_cast<const float4*>(&features[a_base + k0]);
    As[ak + 0][am] = av.x;
    As[ak + 1][am] = av.y;
    As[ak + 2][am] = av.z;
    As[ak + 3][am] = av.w;
    const float4 wv = *reinterpret_cast<const float4*>(
        &W[(size_t)(k0 + wk) * NODE_DIM + col0 + wn]);
    *reinterpret_cast<float4*>(&Ws[wk][wn]) = wv;
    __syncthreads();

#pragma unroll
    for (int k = 0; k < BK; ++k) {
      float ra[4], rb[4];
#pragma unroll
      for (int i = 0; i < 4; ++i) ra[i] = As[k][ty * 4 + i];
#pragma unroll
      for (int j = 0; j < 4; ++j) rb[j] = Ws[k][tx * 4 + j];
#pragma unroll
      for (int i = 0; i < 4; ++i)
#pragma unroll
        for (int j = 0; j < 4; ++j) acc[i][j] += ra[i] * rb[j];
    }
    __syncthreads();
  }

#pragma unroll
  for (int i = 0; i < 4; ++i) {
    const int m = row0 + ty * 4 + i;
#pragma unroll
    for (int j = 0; j < 4; ++j) {
      const int n = col0 + tx * 4 + j;
      l_out[(size_t)m * NODE_DIM + n] = acc[i][j] + bias[n];
    }
  }
}

// ---------------- Kernel 2: scores, grouped argmin, outputs ----------------
// One block (256 thr = 4 waves) per node v. Wave w handles neighbors
// 16w..16w+15. Lanes split the 256 dims (float4 per lane), butterfly reduce.
__global__ __launch_bounds__(256) void sampler_kernel(
    const int* __restrict__ ids,
    const int* __restrict__ adj,
    const float* __restrict__ features,
    const float* __restrict__ l,
    float* __restrict__ out_sel,
    float* __restrict__ out_att,
    float* __restrict__ out_nz1,
    float* __restrict__ out_nz2) {
  __shared__ int   adj_s[MAX_DEG];
  __shared__ float scores_s[MAX_DEG];
  __shared__ float nonpad_s[NSAMP];

  const int v   = blockIdx.x;
  const int tid = threadIdx.x;
  const int nid = ids[v];

  if (tid < MAX_DEG) adj_s[tid] = adj[(size_t)nid * MAX_DEG + tid];
  __syncthreads();

  const int wave = tid >> 6;   // 0..3
  const int lane = tid & 63;

  const float4 lv =
      *reinterpret_cast<const float4*>(&l[(size_t)v * NODE_DIM + lane * 4]);

  for (int kk = 0; kk < 16; ++kk) {
    const int k  = wave * 16 + kk;
    const int nb = adj_s[k];
    const float4 f = *reinterpret_cast<const float4*>(
        &features[(size_t)nb * NODE_DIM + lane * 4]);
    float p = lv.x * f.x + lv.y * f.y + lv.z * f.z + lv.w * f.w;
#pragma unroll
    for (int off = 32; off > 0; off >>= 1) p += __shfl_xor(p, off, 64);
    if (lane == 0) scores_s[k] = p > 0.0f ? p : 0.0f;  // relu
  }
  __syncthreads();

  if (tid < NSAMP) {
    const int s = tid;
    // first-occurrence argmin within group of 4 (strict <, forward scan)
    float best = scores_s[s * GROUP_DIM];
    int   bi   = 0;
#pragma unroll
    for (int g = 1; g < GROUP_DIM; ++g) {
      const float sc = scores_s[s * GROUP_DIM + g];
      if (sc < best) { best = sc; bi = g; }
    }
    const int selid = adj_s[s * GROUP_DIM + bi];
    out_sel[(size_t)v * NSAMP + s] = (float)selid;
    out_att[(size_t)v * NSAMP + s] = 1.0f;
    nonpad_s[s] = (selid == SENTINEL) ? 0.0f : 1.0f;
  }
  __syncthreads();

  if (tid == 0) {
    float nz = 0.0f;
#pragma unroll
    for (int s = 0; s < NSAMP; ++s) nz += nonpad_s[s];
    out_nz1[v] = nz;
    out_nz2[v] = nz;
  }
}

extern "C" void kernel_launch(void* const* d_in, const int* in_sizes, int n_in,
                              void* d_out, int out_size, void* d_ws,
                              size_t ws_size, hipStream_t stream) {
  const int*   ids      = (const int*)d_in[0];
  const int*   adj      = (const int*)d_in[1];
  const float* features = (const float*)d_in[2];
  const float* W        = (const float*)d_in[3];
  const float* bias     = (const float*)d_in[4];
  // d_in[5] = num_samples scalar (fixed at 16 for this problem)

  float* l_ws = (float*)d_ws;  // NUM_V * NODE_DIM floats = 8 MB

  float* out     = (float*)d_out;
  float* out_sel = out;                            // 8192*16
  float* out_att = out + (size_t)NUM_V * NSAMP;    // 8192*16
  float* out_nz1 = out + (size_t)2 * NUM_V * NSAMP;
  float* out_nz2 = out_nz1 + NUM_V;

  gemm_l_kernel<<<dim3(NUM_V / BM, NODE_DIM / BN), 256, 0, stream>>>(
      ids, features, W, bias, l_ws);
  sampler_kernel<<<NUM_V, 256, 0, stream>>>(ids, adj, features, l_ws, out_sel,
                                            out_att, out_nz1, out_nz2);
}

// Round 2
// 239.869 us; speedup vs baseline: 1.0027x; 1.0027x over previous
//
#include <hip/hip_runtime.h>
#include <hip/hip_bf16.h>

// Problem constants (fixed by setup_inputs)
#define N_NODES   100000
#define MAX_DEG   64
#define NODE_DIM  256
#define NUM_V     8192
#define NSAMP     16
#define GROUP_DIM 4
#define SENTINEL  (N_NODES - 1)

// ---------------- Kernel 1: l = features[ids] @ W + b  ----------------
// C[8192x256] = gather(features, ids) @ W + b
// Tile: BM=64 x BN=64, BK=16, 256 threads, 4x4 acc/thread, float4 LDS reads.
#define BM 64
#define BN 64
#define BK 16

__global__ __launch_bounds__(256) void gemm_l_kernel(
    const int* __restrict__ ids,
    const float* __restrict__ features,
    const float* __restrict__ W,
    const float* __restrict__ bias,
    float* __restrict__ l_out) {
  __shared__ float As[BK][BM];   // transposed: As[k][m], row contiguous in m
  __shared__ float Ws[BK][BN];
  __shared__ int   nid_s[BM];

  const int tid  = threadIdx.x;
  const int row0 = blockIdx.x * BM;
  const int col0 = blockIdx.y * BN;

  if (tid < BM) nid_s[tid] = ids[row0 + tid];
  __syncthreads();

  const int tx = tid & 15;   // col group 0..15
  const int ty = tid >> 4;   // row group 0..15

  const int am = tid >> 2;          // 0..63 row within tile
  const int ak = (tid & 3) * 4;     // 0,4,8,12 k offset
  const int wk = tid >> 4;          // 0..15
  const int wn = (tid & 15) * 4;    // 0..60

  const size_t a_base = (size_t)nid_s[am] * NODE_DIM + ak;

  float acc[4][4] = {};

  for (int k0 = 0; k0 < NODE_DIM; k0 += BK) {
    const float4 av = *reinterpret_cast<const float4*>(&features[a_base + k0]);
    As[ak + 0][am] = av.x;
    As[ak + 1][am] = av.y;
    As[ak + 2][am] = av.z;
    As[ak + 3][am] = av.w;
    *reinterpret_cast<float4*>(&Ws[wk][wn]) = *reinterpret_cast<const float4*>(
        &W[(size_t)(k0 + wk) * NODE_DIM + col0 + wn]);
    __syncthreads();

#pragma unroll
    for (int k = 0; k < BK; ++k) {
      const float4 ra = *reinterpret_cast<const float4*>(&As[k][ty * 4]);
      const float4 rb = *reinterpret_cast<const float4*>(&Ws[k][tx * 4]);
      const float a[4] = {ra.x, ra.y, ra.z, ra.w};
      const float b[4] = {rb.x, rb.y, rb.z, rb.w};
#pragma unroll
      for (int i = 0; i < 4; ++i)
#pragma unroll
        for (int j = 0; j < 4; ++j) acc[i][j] += a[i] * b[j];
    }
    __syncthreads();
  }

  const float4 bv =
      *reinterpret_cast<const float4*>(&bias[col0 + tx * 4]);
#pragma unroll
  for (int i = 0; i < 4; ++i) {
    const int m = row0 + ty * 4 + i;
    float4 o;
    o.x = acc[i][0] + bv.x;
    o.y = acc[i][1] + bv.y;
    o.z = acc[i][2] + bv.z;
    o.w = acc[i][3] + bv.w;
    *reinterpret_cast<float4*>(&l_out[(size_t)m * NODE_DIM + col0 + tx * 4]) = o;
  }
}

// ---------------- Kernel 2: scores, grouped argmin, outputs ----------------
// One block (256 thr = 4 waves) per node v. 4 lanes per neighbor:
// quad q (lane>>2) of wave w owns neighbor k = w*16+q. Each lane accumulates
// 64 dims (16 x float4, unrolled -> deep MLP), 2-step quad butterfly finishes
// the dot, 2 more butterfly steps do the grouped first-min argmin in-register.
__global__ __launch_bounds__(256) void sampler_kernel(
    const int* __restrict__ ids,
    const int* __restrict__ adj,
    const float* __restrict__ features,
    const float* __restrict__ l,
    float* __restrict__ out_sel,
    float* __restrict__ out_att,
    float* __restrict__ out_nz1,
    float* __restrict__ out_nz2) {
  __shared__ float l_s[NODE_DIM];
  __shared__ int   adj_s[MAX_DEG];
  __shared__ float nz_s[NSAMP];

  const int v   = blockIdx.x;
  const int tid = threadIdx.x;
  const int nid = ids[v];

  l_s[tid] = l[(size_t)v * NODE_DIM + tid];
  if (tid < MAX_DEG) adj_s[tid] = adj[(size_t)nid * MAX_DEG + tid];
  __syncthreads();

  const int wave = tid >> 6;       // 0..3
  const int lane = tid & 63;
  const int q    = lane >> 2;      // 0..15: neighbor slot within wave
  const int sub  = lane & 3;       // 0..3 : dim-chunk within quad
  const int k    = wave * 16 + q;  // neighbor index 0..63

  const int nb = adj_s[k];
  const float* __restrict__ rowp = features + (size_t)nb * NODE_DIM + sub * 4;
  const float* __restrict__ lp   = l_s + sub * 4;

  float p = 0.0f;
#pragma unroll
  for (int c = 0; c < 16; ++c) {
    const float4 f  = *reinterpret_cast<const float4*>(rowp + c * 16);
    const float4 lv = *reinterpret_cast<const float4*>(lp + c * 16);
    p += f.x * lv.x + f.y * lv.y + f.z * lv.z + f.w * lv.w;
  }
  // finish dot within quad (xor 1, 2): all 4 lanes hold full dot
  p += __shfl_xor(p, 1, 64);
  p += __shfl_xor(p, 2, 64);
  float s = p > 0.0f ? p : 0.0f;   // relu

  // grouped first-occurrence argmin over g = q&3 within 16-lane clusters
  int g = q & 3;
  {
    float os = __shfl_xor(s, 4, 64);
    int   og = __shfl_xor(g, 4, 64);
    if (os < s || (os == s && og < g)) { s = os; g = og; }
    os = __shfl_xor(s, 8, 64);
    og = __shfl_xor(g, 8, 64);
    if (os < s || (os == s && og < g)) { s = os; g = og; }
  }

  if ((lane & 15) == 0) {
    const int gl    = lane >> 4;          // group-local 0..3
    const int s_idx = wave * 4 + gl;      // sample index 0..15
    const int selid = adj_s[s_idx * GROUP_DIM + g];
    out_sel[(size_t)v * NSAMP + s_idx] = (float)selid;
    out_att[(size_t)v * NSAMP + s_idx] = 1.0f;
    nz_s[s_idx] = (selid == SENTINEL) ? 0.0f : 1.0f;
  }
  __syncthreads();

  if (tid == 0) {
    float nz = 0.0f;
#pragma unroll
    for (int t = 0; t < NSAMP; ++t) nz += nz_s[t];
    out_nz1[v] = nz;
    out_nz2[v] = nz;
  }
}

extern "C" void kernel_launch(void* const* d_in, const int* in_sizes, int n_in,
                              void* d_out, int out_size, void* d_ws,
                              size_t ws_size, hipStream_t stream) {
  const int*   ids      = (const int*)d_in[0];
  const int*   adj      = (const int*)d_in[1];
  const float* features = (const float*)d_in[2];
  const float* W        = (const float*)d_in[3];
  const float* bias     = (const float*)d_in[4];

  float* l_ws = (float*)d_ws;  // NUM_V * NODE_DIM floats = 8 MB

  float* out     = (float*)d_out;
  float* out_sel = out;
  float* out_att = out + (size_t)NUM_V * NSAMP;
  float* out_nz1 = out + (size_t)2 * NUM_V * NSAMP;
  float* out_nz2 = out_nz1 + NUM_V;

  gemm_l_kernel<<<dim3(NUM_V / BM, NODE_DIM / BN), 256, 0, stream>>>(
      ids, features, W, bias, l_ws);
  sampler_kernel<<<NUM_V, 256, 0, stream>>>(ids, adj, features, l_ws, out_sel,
                                            out_att, out_nz1, out_nz2);
}

// Round 3
// 236.062 us; speedup vs baseline: 1.0189x; 1.0161x over previous
//
#include <hip/hip_runtime.h>
#include <hip/hip_bf16.h>

// Problem constants (fixed by setup_inputs)
#define N_NODES   100000
#define MAX_DEG   64
#define NODE_DIM  256
#define NUM_V     8192
#define NSAMP     16
#define GROUP_DIM 4
#define SENTINEL  (N_NODES - 1)

// ---------------- Kernel 1: l = features[ids] @ W + b  ----------------
// C[8192x256] = gather(features, ids) @ W + b
// BM=64 x BN=64, BK=32, 256 threads, 4x4 acc/thread.
// Register-prefetch double buffer: global loads for tile k0+1 are issued
// immediately after staging tile k0 to LDS, overlapping the 32-step FMA loop.
// As padded to stride 68 -> ds_write conflicts drop to 2-way (free on gfx950).
#define BM 64
#define BN 64
#define BK 32
#define AS_STRIDE (BM + 4)

__global__ __launch_bounds__(256) void gemm_l_kernel(
    const int* __restrict__ ids,
    const float* __restrict__ features,
    const float* __restrict__ W,
    const float* __restrict__ bias,
    float* __restrict__ l_out) {
  __shared__ float As[BK][AS_STRIDE];
  __shared__ float Ws[BK][BN];
  __shared__ int   nid_s[BM];

  const int tid  = threadIdx.x;
  const int row0 = blockIdx.x * BM;
  const int col0 = blockIdx.y * BN;

  if (tid < BM) nid_s[tid] = ids[row0 + tid];
  __syncthreads();

  const int tx = tid & 15;   // col group 0..15
  const int ty = tid >> 4;   // row group 0..15

  // A staging: thread owns row am, two 16B chunks at k = ak and ak+16
  const int am = tid >> 2;          // 0..63
  const int ak = (tid & 3) * 4;     // 0,4,8,12
  // W staging: two 16B chunks at k-rows wk and wk+16
  const int wk = tid >> 4;          // 0..15
  const int wn = (tid & 15) * 4;    // 0..60

  const size_t a_base = (size_t)nid_s[am] * NODE_DIM + ak;
  const size_t w_base = (size_t)wk * NODE_DIM + col0 + wn;

  float4 av0, av1, wv0, wv1;
  // prefetch tile k0 = 0
  av0 = *reinterpret_cast<const float4*>(&features[a_base]);
  av1 = *reinterpret_cast<const float4*>(&features[a_base + 16]);
  wv0 = *reinterpret_cast<const float4*>(&W[w_base]);
  wv1 = *reinterpret_cast<const float4*>(&W[w_base + 16 * NODE_DIM]);

  float acc[4][4] = {};

  for (int k0 = 0; k0 < NODE_DIM; k0 += BK) {
    // stage current tile
    As[ak + 0][am] = av0.x;
    As[ak + 1][am] = av0.y;
    As[ak + 2][am] = av0.z;
    As[ak + 3][am] = av0.w;
    As[ak + 16 + 0][am] = av1.x;
    As[ak + 16 + 1][am] = av1.y;
    As[ak + 16 + 2][am] = av1.z;
    As[ak + 16 + 3][am] = av1.w;
    *reinterpret_cast<float4*>(&Ws[wk][wn])      = wv0;
    *reinterpret_cast<float4*>(&Ws[wk + 16][wn]) = wv1;
    __syncthreads();

    // issue next tile's global loads now; they drain during the FMA loop
    if (k0 + BK < NODE_DIM) {
      const int kn = k0 + BK;
      av0 = *reinterpret_cast<const float4*>(&features[a_base + kn]);
      av1 = *reinterpret_cast<const float4*>(&features[a_base + kn + 16]);
      wv0 = *reinterpret_cast<const float4*>(&W[w_base + (size_t)kn * NODE_DIM]);
      wv1 = *reinterpret_cast<const float4*>(
          &W[w_base + (size_t)(kn + 16) * NODE_DIM]);
    }

#pragma unroll
    for (int k = 0; k < BK; ++k) {
      const float4 ra = *reinterpret_cast<const float4*>(&As[k][ty * 4]);
      const float4 rb = *reinterpret_cast<const float4*>(&Ws[k][tx * 4]);
      const float a[4] = {ra.x, ra.y, ra.z, ra.w};
      const float b[4] = {rb.x, rb.y, rb.z, rb.w};
#pragma unroll
      for (int i = 0; i < 4; ++i)
#pragma unroll
        for (int j = 0; j < 4; ++j) acc[i][j] += a[i] * b[j];
    }
    __syncthreads();
  }

  const float4 bv = *reinterpret_cast<const float4*>(&bias[col0 + tx * 4]);
#pragma unroll
  for (int i = 0; i < 4; ++i) {
    const int m = row0 + ty * 4 + i;
    float4 o;
    o.x = acc[i][0] + bv.x;
    o.y = acc[i][1] + bv.y;
    o.z = acc[i][2] + bv.z;
    o.w = acc[i][3] + bv.w;
    *reinterpret_cast<float4*>(&l_out[(size_t)m * NODE_DIM + col0 + tx * 4]) = o;
  }
}

// ---------------- Kernel 2: scores, grouped argmin, outputs ----------------
// UNCHANGED from R2 (pinned at 86 us / 257 MB L2-miss / ~3.1 TB/s — miss-path
// bound; two structurally different versions timed identically).
__global__ __launch_bounds__(256) void sampler_kernel(
    const int* __restrict__ ids,
    const int* __restrict__ adj,
    const float* __restrict__ features,
    const float* __restrict__ l,
    float* __restrict__ out_sel,
    float* __restrict__ out_att,
    float* __restrict__ out_nz1,
    float* __restrict__ out_nz2) {
  __shared__ float l_s[NODE_DIM];
  __shared__ int   adj_s[MAX_DEG];
  __shared__ float nz_s[NSAMP];

  const int v   = blockIdx.x;
  const int tid = threadIdx.x;
  const int nid = ids[v];

  l_s[tid] = l[(size_t)v * NODE_DIM + tid];
  if (tid < MAX_DEG) adj_s[tid] = adj[(size_t)nid * MAX_DEG + tid];
  __syncthreads();

  const int wave = tid >> 6;       // 0..3
  const int lane = tid & 63;
  const int q    = lane >> 2;      // 0..15: neighbor slot within wave
  const int sub  = lane & 3;       // 0..3 : dim-chunk within quad
  const int k    = wave * 16 + q;  // neighbor index 0..63

  const int nb = adj_s[k];
  const float* __restrict__ rowp = features + (size_t)nb * NODE_DIM + sub * 4;
  const float* __restrict__ lp   = l_s + sub * 4;

  float p = 0.0f;
#pragma unroll
  for (int c = 0; c < 16; ++c) {
    const float4 f  = *reinterpret_cast<const float4*>(rowp + c * 16);
    const float4 lv = *reinterpret_cast<const float4*>(lp + c * 16);
    p += f.x * lv.x + f.y * lv.y + f.z * lv.z + f.w * lv.w;
  }
  p += __shfl_xor(p, 1, 64);
  p += __shfl_xor(p, 2, 64);
  float s = p > 0.0f ? p : 0.0f;   // relu

  int g = q & 3;
  {
    float os = __shfl_xor(s, 4, 64);
    int   og = __shfl_xor(g, 4, 64);
    if (os < s || (os == s && og < g)) { s = os; g = og; }
    os = __shfl_xor(s, 8, 64);
    og = __shfl_xor(g, 8, 64);
    if (os < s || (os == s && og < g)) { s = os; g = og; }
  }

  if ((lane & 15) == 0) {
    const int gl    = lane >> 4;
    const int s_idx = wave * 4 + gl;
    const int selid = adj_s[s_idx * GROUP_DIM + g];
    out_sel[(size_t)v * NSAMP + s_idx] = (float)selid;
    out_att[(size_t)v * NSAMP + s_idx] = 1.0f;
    nz_s[s_idx] = (selid == SENTINEL) ? 0.0f : 1.0f;
  }
  __syncthreads();

  if (tid == 0) {
    float nz = 0.0f;
#pragma unroll
    for (int t = 0; t < NSAMP; ++t) nz += nz_s[t];
    out_nz1[v] = nz;
    out_nz2[v] = nz;
  }
}

extern "C" void kernel_launch(void* const* d_in, const int* in_sizes, int n_in,
                              void* d_out, int out_size, void* d_ws,
                              size_t ws_size, hipStream_t stream) {
  const int*   ids      = (const int*)d_in[0];
  const int*   adj      = (const int*)d_in[1];
  const float* features = (const float*)d_in[2];
  const float* W        = (const float*)d_in[3];
  const float* bias     = (const float*)d_in[4];

  float* l_ws = (float*)d_ws;  // NUM_V * NODE_DIM floats = 8 MB

  float* out     = (float*)d_out;
  float* out_sel = out;
  float* out_att = out + (size_t)NUM_V * NSAMP;
  float* out_nz1 = out + (size_t)2 * NUM_V * NSAMP;
  float* out_nz2 = out_nz1 + NUM_V;

  gemm_l_kernel<<<dim3(NUM_V / BM, NODE_DIM / BN), 256, 0, stream>>>(
      ids, features, W, bias, l_ws);
  sampler_kernel<<<NUM_V, 256, 0, stream>>>(ids, adj, features, l_ws, out_sel,
                                            out_att, out_nz1, out_nz2);
}